// Round 1
// baseline (1462.260 us; speedup 1.0000x reference)
//
#include <hip/hip_runtime.h>
#include <cstdint>
#include <cstddef>

// Problem constants
#define BATCH   4
#define L_SEQ   2048
#define DMODEL  1024
#define NHEAD   4
#define HDIM    256
#define FFDIM   4096
#define MROWS   (BATCH * L_SEQ)   // 8192
#define NLAYER  2

typedef __bf16 bf16_t;
typedef __bf16 bf16x8 __attribute__((ext_vector_type(8)));
typedef __bf16 bf16x4 __attribute__((ext_vector_type(4)));
typedef float  floatx4 __attribute__((ext_vector_type(4)));

// ---------------------------------------------------------------------------
// async global->LDS 16B copy (wave-uniform LDS base + lane*16; CK-style casts)
// ---------------------------------------------------------------------------
__device__ __forceinline__ void async_cp16(const void* g, void* l) {
  auto gp = reinterpret_cast<__attribute__((address_space(1))) void*>(
      reinterpret_cast<uintptr_t>(g));
  auto lp = reinterpret_cast<__attribute__((address_space(3))) void*>(
      reinterpret_cast<uintptr_t>(l));
  __builtin_amdgcn_global_load_lds(gp, lp, 16, 0, 0);
}

// ---------------------------------------------------------------------------
// f32 -> bf16 convert (vectorized)
// ---------------------------------------------------------------------------
__global__ __launch_bounds__(256)
void cvt_f32_bf16(const float* __restrict__ in, bf16_t* __restrict__ out, int n4) {
  int i = blockIdx.x * 256 + threadIdx.x;
  if (i >= n4) return;
  float4 v = ((const float4*)in)[i];
  bf16x4 ov = { (bf16_t)v.x, (bf16_t)v.y, (bf16_t)v.z, (bf16_t)v.w };
  ((bf16x4*)out)[i] = ov;
}

// ---------------------------------------------------------------------------
// LayerNorm: one block (256 threads) per row of D=1024, fp32 math.
// BF16OUT=true -> bf16 output (GEMM input), false -> fp32 output (d_out)
// ---------------------------------------------------------------------------
template<bool BF16OUT>
__global__ __launch_bounds__(256)
void ln_kernel(const float* __restrict__ x, const float* __restrict__ gw,
               const float* __restrict__ bw, void* __restrict__ outp) {
  const int row = blockIdx.x;
  const int tid = threadIdx.x;
  const float4 v = ((const float4*)(x + (size_t)row * DMODEL))[tid];
  float s  = v.x + v.y + v.z + v.w;
  float ss = v.x * v.x + v.y * v.y + v.z * v.z + v.w * v.w;
#pragma unroll
  for (int o = 32; o > 0; o >>= 1) {
    s  += __shfl_xor(s, o);
    ss += __shfl_xor(ss, o);
  }
  __shared__ float red0[4], red1[4];
  const int wv = tid >> 6;
  if ((tid & 63) == 0) { red0[wv] = s; red1[wv] = ss; }
  __syncthreads();
  s  = red0[0] + red0[1] + red0[2] + red0[3];
  ss = red1[0] + red1[1] + red1[2] + red1[3];
  const float mu  = s * (1.0f / DMODEL);
  const float var = ss * (1.0f / DMODEL) - mu * mu;
  const float rs  = rsqrtf(var + 1e-5f);
  const float4 g4 = ((const float4*)gw)[tid];
  const float4 b4 = ((const float4*)bw)[tid];
  const float o0 = (v.x - mu) * rs * g4.x + b4.x;
  const float o1 = (v.y - mu) * rs * g4.y + b4.y;
  const float o2 = (v.z - mu) * rs * g4.z + b4.z;
  const float o3 = (v.w - mu) * rs * g4.w + b4.w;
  if (BF16OUT) {
    bf16x4 ov = { (bf16_t)o0, (bf16_t)o1, (bf16_t)o2, (bf16_t)o3 };
    ((bf16x4*)outp)[(size_t)row * (DMODEL / 4) + tid] = ov;
  } else {
    float4 ov = { o0, o1, o2, o3 };
    ((float4*)outp)[(size_t)row * (DMODEL / 4) + tid] = ov;
  }
}

// ---------------------------------------------------------------------------
// Softmax in-place over rows of length L_SEQ (bf16 storage, fp32 math).
// One block per row, 256 threads * 8 elems.
// ---------------------------------------------------------------------------
__global__ __launch_bounds__(256)
void softmax_kernel(bf16_t* __restrict__ S) {
  const size_t row = blockIdx.x;
  bf16_t* p = S + row * (size_t)L_SEQ + (size_t)threadIdx.x * 8;
  bf16x8 rv = *(const bf16x8*)p;
  float v[8];
  float mx = -1e30f;
#pragma unroll
  for (int j = 0; j < 8; ++j) { v[j] = (float)rv[j]; mx = fmaxf(mx, v[j]); }
#pragma unroll
  for (int o = 32; o > 0; o >>= 1) mx = fmaxf(mx, __shfl_xor(mx, o));
  __shared__ float sm[4], ssum[4];
  const int lane = threadIdx.x & 63, wv = threadIdx.x >> 6;
  if (lane == 0) sm[wv] = mx;
  __syncthreads();
  mx = fmaxf(fmaxf(sm[0], sm[1]), fmaxf(sm[2], sm[3]));
  float sum = 0.0f;
#pragma unroll
  for (int j = 0; j < 8; ++j) { v[j] = __expf(v[j] - mx); sum += v[j]; }
#pragma unroll
  for (int o = 32; o > 0; o >>= 1) sum += __shfl_xor(sum, o);
  if (lane == 0) ssum[wv] = sum;
  __syncthreads();
  sum = ssum[0] + ssum[1] + ssum[2] + ssum[3];
  const float inv = 1.0f / sum;
  bf16x8 ov;
#pragma unroll
  for (int j = 0; j < 8; ++j) ov[j] = (bf16_t)(v[j] * inv);
  *(bf16x8*)p = ov;
}

// ---------------------------------------------------------------------------
// V transpose: v_tmp (b, l, head*HDIM+hd) -> vT (b*H+head, hd, l)
// grid (L/64, HDIM/64, B*H), 256 threads, LDS 64x65 tile
// ---------------------------------------------------------------------------
__global__ __launch_bounds__(256)
void transpose_v(const bf16_t* __restrict__ vt, bf16_t* __restrict__ vT) {
  __shared__ bf16_t tile[64][65];
  const int z = blockIdx.z, b = z >> 2, head = z & 3;
  const int l0 = blockIdx.x * 64, hd0 = blockIdx.y * 64;
  const int x = threadIdx.x & 63, y4 = threadIdx.x >> 6;
#pragma unroll
  for (int r = 0; r < 64; r += 4) {
    const int l = l0 + y4 + r;
    tile[y4 + r][x] =
        vt[((size_t)b * L_SEQ + l) * DMODEL + head * HDIM + hd0 + x];
  }
  __syncthreads();
#pragma unroll
  for (int r = 0; r < 64; r += 4) {
    const int hd = hd0 + y4 + r;
    vT[((size_t)z * HDIM + hd) * L_SEQ + l0 + x] = tile[x][y4 + r];
  }
}

// ---------------------------------------------------------------------------
// Epilogue functors for the GEMM
// ---------------------------------------------------------------------------
struct EpiBiasF32 {          // C = acc + bias[n], fp32
  float* C; const float* bias; int ldc;
  __device__ __forceinline__ void store(int, int m, int n, float v) const {
    C[(size_t)m * ldc + n] = v + bias[n];
  }
};
struct EpiResBiasF32 {       // C += acc + bias[n], fp32 (residual stream)
  float* C; const float* bias; int ldc;
  __device__ __forceinline__ void store(int, int m, int n, float v) const {
    const size_t idx = (size_t)m * ldc + n;
    C[idx] = C[idx] + v + bias[n];
  }
};
struct EpiGeluBf16 {         // C = gelu(acc + bias[n]) -> bf16 (exact erf gelu)
  bf16_t* C; const float* bias; int ldc;
  __device__ __forceinline__ void store(int, int m, int n, float v) const {
    const float t = v + bias[n];
    const float g = 0.5f * t * (1.0f + erff(t * 0.7071067811865475f));
    C[(size_t)m * ldc + n] = (bf16_t)g;
  }
};
struct EpiQKV {              // scatter q,k to (b,h,L,HD); v to (b,l,D) tmp
  bf16_t *q, *k, *vt; const float* bias;
  __device__ __forceinline__ void store(int, int m, int n, float v) const {
    const float t = v + bias[n];
    const int b = m >> 11, l = m & 2047;        // m = b*L + l
    const int which = n >> 10, e = n & 1023;    // n = which*D + head*HD + hd
    const int head = e >> 8, hd = e & 255;
    const bf16_t x = (bf16_t)t;
    if (which == 0)
      q[(((size_t)(b * NHEAD + head)) * L_SEQ + l) * HDIM + hd] = x;
    else if (which == 1)
      k[(((size_t)(b * NHEAD + head)) * L_SEQ + l) * HDIM + hd] = x;
    else
      vt[(size_t)m * DMODEL + e] = x;
  }
};
struct EpiScaleBf16 {        // scores: C[z] = acc * scale -> bf16
  bf16_t* C; long strideC; int ldc; float scale;
  __device__ __forceinline__ void store(int z, int m, int n, float v) const {
    C[(size_t)z * strideC + (size_t)m * ldc + n] = (bf16_t)(v * scale);
  }
};
struct EpiOBf16 {            // PV out: o[b][l][head*HD+hd] -> bf16, z = b*H+head
  bf16_t* C;
  __device__ __forceinline__ void store(int z, int m, int n, float v) const {
    C[((size_t)(z >> 2) * L_SEQ + m) * DMODEL + (z & 3) * HDIM + n] = (bf16_t)v;
  }
};

// ---------------------------------------------------------------------------
// bf16 GEMM: C[m,n] = sum_k A[m,k] * B[n,k]  (B given transposed, row-major NxK)
// BM=BN=128, BK=32; 256 threads = 4 waves in 2x2, each wave 4x4 MFMA 16x16x32.
// Staging via global_load_lds width 16 (m97 structure). Batched via blockIdx.z.
// All M,N multiples of 128; K multiple of 32. lda/ldb multiples of 8.
// ---------------------------------------------------------------------------
template<class Epi>
__global__ __launch_bounds__(256, 2)
void gemm_bt(const bf16_t* __restrict__ A, int lda, long strideA,
             const bf16_t* __restrict__ B, int ldb, long strideB,
             int K, Epi epi) {
  __shared__ bf16_t lsA[128 * 32];
  __shared__ bf16_t lsB[128 * 32];
  const int tid  = threadIdx.x;
  const int wave = tid >> 6, lane = tid & 63;
  const int z = blockIdx.z;
  A += (size_t)z * strideA;
  B += (size_t)z * strideB;
  const int m0 = blockIdx.y * 128, n0 = blockIdx.x * 128;

  // staging coords: chunk = wave*2+j covers 16 rows; lane covers (row=lane/4, col=(lane&3)*8)
  const int c   = (lane & 3) * 8;
  const int r0  = (wave * 2 + 0) * 16 + (lane >> 2);
  const int r1  = (wave * 2 + 1) * 16 + (lane >> 2);
  const bf16_t* ga0 = A + (size_t)(m0 + r0) * lda + c;
  const bf16_t* ga1 = A + (size_t)(m0 + r1) * lda + c;
  const bf16_t* gb0 = B + (size_t)(n0 + r0) * ldb + c;
  const bf16_t* gb1 = B + (size_t)(n0 + r1) * ldb + c;
  bf16_t* la0 = &lsA[(wave * 2 + 0) * 512];
  bf16_t* la1 = &lsA[(wave * 2 + 1) * 512];
  bf16_t* lb0 = &lsB[(wave * 2 + 0) * 512];
  bf16_t* lb1 = &lsB[(wave * 2 + 1) * 512];

  const int wm = wave >> 1, wn = wave & 1;
  const int lane15 = lane & 15, quad = lane >> 4;
  const int aoff = (wm * 64 + lane15) * 32 + quad * 8;  // + i*512 per m-tile
  const int boff = (wn * 64 + lane15) * 32 + quad * 8;  // + j*512 per n-tile

  floatx4 acc[4][4] = {};

  for (int k0 = 0; k0 < K; k0 += 32) {
    async_cp16(ga0 + k0, la0);
    async_cp16(ga1 + k0, la1);
    async_cp16(gb0 + k0, lb0);
    async_cp16(gb1 + k0, lb1);
    __syncthreads();
    bf16x8 af[4], bfr[4];
#pragma unroll
    for (int i = 0; i < 4; ++i) af[i]  = *(const bf16x8*)&lsA[aoff + i * 512];
#pragma unroll
    for (int i = 0; i < 4; ++i) bfr[i] = *(const bf16x8*)&lsB[boff + i * 512];
#pragma unroll
    for (int i = 0; i < 4; ++i)
#pragma unroll
      for (int j = 0; j < 4; ++j)
        acc[i][j] = __builtin_amdgcn_mfma_f32_16x16x32_bf16(af[i], bfr[j],
                                                            acc[i][j], 0, 0, 0);
    __syncthreads();
  }

  // epilogue: C/D layout col = lane&15, row = quad*4 + reg (m89-verified)
#pragma unroll
  for (int i = 0; i < 4; ++i) {
    const int mbase = m0 + wm * 64 + i * 16 + quad * 4;
#pragma unroll
    for (int j = 0; j < 4; ++j) {
      const int nloc = n0 + wn * 64 + j * 16 + lane15;
#pragma unroll
      for (int r = 0; r < 4; ++r)
        epi.store(z, mbase + r, nloc, acc[i][j][r]);
    }
  }
}

// ---------------------------------------------------------------------------
// Host launcher
// ---------------------------------------------------------------------------
extern "C" void kernel_launch(void* const* d_in, const int* in_sizes, int n_in,
                              void* d_out, int out_size, void* d_ws, size_t ws_size,
                              hipStream_t stream) {
  const float* x_in  = (const float*)d_in[0];
  const float* w3d   = (const float*)d_in[1];
  const float* b3d   = (const float*)d_in[2];
  const float* ln1g  = (const float*)d_in[3];
  const float* ln1b  = (const float*)d_in[4];
  const float* wqkv  = (const float*)d_in[5];
  const float* bqkv  = (const float*)d_in[6];
  const float* wproj = (const float*)d_in[7];
  const float* bproj = (const float*)d_in[8];
  const float* ln2g  = (const float*)d_in[9];
  const float* ln2b  = (const float*)d_in[10];
  const float* w1    = (const float*)d_in[11];
  const float* b1    = (const float*)d_in[12];
  const float* w2    = (const float*)d_in[13];
  const float* b2    = (const float*)d_in[14];
  const float* lnfg  = (const float*)d_in[15];
  const float* lnfb  = (const float*)d_in[16];
  float* out = (float*)d_out;

  // ---- workspace carve-up (~325 MB; unions: xb ≡ q/k/v_tmp, S ≡ f) ----
  char* ws = (char*)d_ws;
  size_t off = 0;
  auto alloc = [&](size_t bytes) -> void* {
    void* p = ws + off;
    off = (off + bytes + 255) & ~(size_t)255;
    return p;
  };
  float*  h      = (float*) alloc((size_t)MROWS * DMODEL * 4);       // 32 MB
  bf16_t* hn     = (bf16_t*)alloc((size_t)MROWS * DMODEL * 2);       // 16 MB
  bf16_t* w3db   = (bf16_t*)alloc((size_t)DMODEL * 3 * DMODEL * 2);  //  6 MB
  bf16_t* wqkvb  = (bf16_t*)alloc((size_t)NLAYER * 3 * DMODEL * DMODEL * 2);
  bf16_t* wprojb = (bf16_t*)alloc((size_t)NLAYER * DMODEL * DMODEL * 2);
  bf16_t* w1b    = (bf16_t*)alloc((size_t)NLAYER * FFDIM * DMODEL * 2);
  bf16_t* w2b    = (bf16_t*)alloc((size_t)NLAYER * DMODEL * FFDIM * 2);
  char*   r1     = (char*)  alloc(3ull * 16777216);                  // 48 MB
  bf16_t* xb     = (bf16_t*)r1;                    // (B,L,3D) bf16 (pre-layers)
  bf16_t* qb     = (bf16_t*)r1;                    // (B,H,L,HD)
  bf16_t* kb     = (bf16_t*)(r1 + 16777216);       // (B,H,L,HD)
  bf16_t* vtmp   = (bf16_t*)(r1 + 2ull * 16777216);// (B,L,D)
  bf16_t* vT     = (bf16_t*)alloc(16777216);       // (B*H, HD, L)
  bf16_t* ob     = (bf16_t*)alloc(16777216);       // (B,L,D)
  char*   r2     = (char*)  alloc(134217728);      // 128 MB
  bf16_t* S      = (bf16_t*)r2;                    // (B*H, L, L) scores/probs
  bf16_t* f      = (bf16_t*)r2;                    // (B*L, FF) gelu out
  (void)ws_size; (void)in_sizes; (void)n_in; (void)out_size;

  // ---- convert inputs/weights to bf16 ----
  auto cvt = [&](const float* src, bf16_t* dst, size_t n) {
    int n4 = (int)(n / 4);
    cvt_f32_bf16<<<(n4 + 255) / 256, 256, 0, stream>>>(src, dst, n4);
  };
  cvt(x_in,  xb,     (size_t)MROWS * 3 * DMODEL);
  cvt(w3d,   w3db,   (size_t)DMODEL * 3 * DMODEL);
  cvt(wqkv,  wqkvb,  (size_t)NLAYER * 3 * DMODEL * DMODEL);
  cvt(wproj, wprojb, (size_t)NLAYER * DMODEL * DMODEL);
  cvt(w1,    w1b,    (size_t)NLAYER * FFDIM * DMODEL);
  cvt(w2,    w2b,    (size_t)NLAYER * DMODEL * FFDIM);

  // ---- initial projection: h = x @ w3d^T + b3d   (M=8192,N=1024,K=3072) ----
  gemm_bt<<<dim3(DMODEL / 128, MROWS / 128, 1), 256, 0, stream>>>(
      xb, 3 * DMODEL, 0L, w3db, 3 * DMODEL, 0L, 3 * DMODEL,
      EpiBiasF32{h, b3d, DMODEL});

  for (int i = 0; i < NLAYER; ++i) {
    // ln1 -> hn (bf16)
    ln_kernel<true><<<MROWS, 256, 0, stream>>>(h, ln1g + i * DMODEL,
                                               ln1b + i * DMODEL, hn);
    // qkv = hn @ wqkv[i]^T + bqkv[i], scattered to q,k,v_tmp
    gemm_bt<<<dim3(3 * DMODEL / 128, MROWS / 128, 1), 256, 0, stream>>>(
        hn, DMODEL, 0L, wqkvb + (size_t)i * 3 * DMODEL * DMODEL, DMODEL, 0L,
        DMODEL, EpiQKV{qb, kb, vtmp, bqkv + i * 3 * DMODEL});
    // v_tmp -> vT
    transpose_v<<<dim3(L_SEQ / 64, HDIM / 64, BATCH * NHEAD), 256, 0, stream>>>(
        vtmp, vT);
    // scores: S[z] = q[z] @ k[z]^T * 1/16   (M=N=2048, K=256, z=16)
    gemm_bt<<<dim3(L_SEQ / 128, L_SEQ / 128, BATCH * NHEAD), 256, 0, stream>>>(
        qb, HDIM, (long)L_SEQ * HDIM, kb, HDIM, (long)L_SEQ * HDIM, HDIM,
        EpiScaleBf16{S, (long)L_SEQ * L_SEQ, L_SEQ, 0.0625f});
    // softmax rows (in place)
    softmax_kernel<<<BATCH * NHEAD * L_SEQ, 256, 0, stream>>>(S);
    // o[z] = P[z] @ vT[z]^T   (M=2048, N=256, K=2048, z=16)
    gemm_bt<<<dim3(HDIM / 128, L_SEQ / 128, BATCH * NHEAD), 256, 0, stream>>>(
        S, L_SEQ, (long)L_SEQ * L_SEQ, vT, L_SEQ, (long)HDIM * L_SEQ, L_SEQ,
        EpiOBf16{ob});
    // h += o @ wproj[i]^T + bproj[i]
    gemm_bt<<<dim3(DMODEL / 128, MROWS / 128, 1), 256, 0, stream>>>(
        ob, DMODEL, 0L, wprojb + (size_t)i * DMODEL * DMODEL, DMODEL, 0L,
        DMODEL, EpiResBiasF32{h, bproj + i * DMODEL, DMODEL});
    // ln2 -> hn
    ln_kernel<true><<<MROWS, 256, 0, stream>>>(h, ln2g + i * DMODEL,
                                               ln2b + i * DMODEL, hn);
    // f = gelu(hn @ w1[i]^T + b1[i])  (N=4096)
    gemm_bt<<<dim3(FFDIM / 128, MROWS / 128, 1), 256, 0, stream>>>(
        hn, DMODEL, 0L, w1b + (size_t)i * FFDIM * DMODEL, DMODEL, 0L, DMODEL,
        EpiGeluBf16{f, b1 + i * FFDIM, FFDIM});
    // h += f @ w2[i]^T + b2[i]  (K=4096)
    gemm_bt<<<dim3(DMODEL / 128, MROWS / 128, 1), 256, 0, stream>>>(
        f, FFDIM, 0L, w2b + (size_t)i * DMODEL * FFDIM, FFDIM, 0L, FFDIM,
        EpiResBiasF32{h, b2 + i * DMODEL, DMODEL});
  }

  // final layernorm -> fp32 out
  ln_kernel<false><<<MROWS, 256, 0, stream>>>(h, lnfg, lnfb, out);
}

// Round 2
// 1322.642 us; speedup vs baseline: 1.1056x; 1.1056x over previous
//
#include <hip/hip_runtime.h>
#include <cstdint>
#include <cstddef>

// Problem constants
#define BATCH   4
#define L_SEQ   2048
#define DMODEL  1024
#define NHEAD   4
#define HDIM    256
#define FFDIM   4096
#define MROWS   (BATCH * L_SEQ)   // 8192
#define NLAYER  2

typedef __bf16 bf16_t;
typedef __bf16 bf16x8 __attribute__((ext_vector_type(8)));
typedef __bf16 bf16x4 __attribute__((ext_vector_type(4)));
typedef float  floatx4 __attribute__((ext_vector_type(4)));

// ---------------------------------------------------------------------------
// async global->LDS 16B copy. LDS dest = wave-uniform base + lane*16 (HW rule).
// ---------------------------------------------------------------------------
__device__ __forceinline__ void async_cp16(const void* g, void* l) {
  auto gp = reinterpret_cast<__attribute__((address_space(1))) void*>(
      reinterpret_cast<uintptr_t>(g));
  auto lp = reinterpret_cast<__attribute__((address_space(3))) void*>(
      reinterpret_cast<uintptr_t>(l));
  __builtin_amdgcn_global_load_lds(gp, lp, 16, 0, 0);
}

// ---------------------------------------------------------------------------
// f32 -> bf16 convert (vectorized)
// ---------------------------------------------------------------------------
__global__ __launch_bounds__(256)
void cvt_f32_bf16(const float* __restrict__ in, bf16_t* __restrict__ out, int n4) {
  int i = blockIdx.x * 256 + threadIdx.x;
  if (i >= n4) return;
  float4 v = ((const float4*)in)[i];
  bf16x4 ov = { (bf16_t)v.x, (bf16_t)v.y, (bf16_t)v.z, (bf16_t)v.w };
  ((bf16x4*)out)[i] = ov;
}

// ---------------------------------------------------------------------------
// LayerNorm: one block (256 threads) per row of D=1024, fp32 math.
// ---------------------------------------------------------------------------
template<bool BF16OUT>
__global__ __launch_bounds__(256)
void ln_kernel(const float* __restrict__ x, const float* __restrict__ gw,
               const float* __restrict__ bw, void* __restrict__ outp) {
  const int row = blockIdx.x;
  const int tid = threadIdx.x;
  const float4 v = ((const float4*)(x + (size_t)row * DMODEL))[tid];
  float s  = v.x + v.y + v.z + v.w;
  float ss = v.x * v.x + v.y * v.y + v.z * v.z + v.w * v.w;
#pragma unroll
  for (int o = 32; o > 0; o >>= 1) {
    s  += __shfl_xor(s, o);
    ss += __shfl_xor(ss, o);
  }
  __shared__ float red0[4], red1[4];
  const int wv = tid >> 6;
  if ((tid & 63) == 0) { red0[wv] = s; red1[wv] = ss; }
  __syncthreads();
  s  = red0[0] + red0[1] + red0[2] + red0[3];
  ss = red1[0] + red1[1] + red1[2] + red1[3];
  const float mu  = s * (1.0f / DMODEL);
  const float var = ss * (1.0f / DMODEL) - mu * mu;
  const float rs  = rsqrtf(var + 1e-5f);
  const float4 g4 = ((const float4*)gw)[tid];
  const float4 b4 = ((const float4*)bw)[tid];
  const float o0 = (v.x - mu) * rs * g4.x + b4.x;
  const float o1 = (v.y - mu) * rs * g4.y + b4.y;
  const float o2 = (v.z - mu) * rs * g4.z + b4.z;
  const float o3 = (v.w - mu) * rs * g4.w + b4.w;
  if (BF16OUT) {
    bf16x4 ov = { (bf16_t)o0, (bf16_t)o1, (bf16_t)o2, (bf16_t)o3 };
    ((bf16x4*)outp)[(size_t)row * (DMODEL / 4) + tid] = ov;
  } else {
    float4 ov = { o0, o1, o2, o3 };
    ((float4*)outp)[(size_t)row * (DMODEL / 4) + tid] = ov;
  }
}

// ---------------------------------------------------------------------------
// Softmax in-place over rows of length L_SEQ (bf16 storage, fp32 math).
// ---------------------------------------------------------------------------
__global__ __launch_bounds__(256)
void softmax_kernel(bf16_t* __restrict__ S) {
  const size_t row = blockIdx.x;
  bf16_t* p = S + row * (size_t)L_SEQ + (size_t)threadIdx.x * 8;
  bf16x8 rv = *(const bf16x8*)p;
  float v[8];
  float mx = -1e30f;
#pragma unroll
  for (int j = 0; j < 8; ++j) { v[j] = (float)rv[j]; mx = fmaxf(mx, v[j]); }
#pragma unroll
  for (int o = 32; o > 0; o >>= 1) mx = fmaxf(mx, __shfl_xor(mx, o));
  __shared__ float sm[4], ssum[4];
  const int lane = threadIdx.x & 63, wv = threadIdx.x >> 6;
  if (lane == 0) sm[wv] = mx;
  __syncthreads();
  mx = fmaxf(fmaxf(sm[0], sm[1]), fmaxf(sm[2], sm[3]));
  float sum = 0.0f;
#pragma unroll
  for (int j = 0; j < 8; ++j) { v[j] = __expf(v[j] - mx); sum += v[j]; }
#pragma unroll
  for (int o = 32; o > 0; o >>= 1) sum += __shfl_xor(sum, o);
  if (lane == 0) ssum[wv] = sum;
  __syncthreads();
  sum = ssum[0] + ssum[1] + ssum[2] + ssum[3];
  const float inv = 1.0f / sum;
  bf16x8 ov;
#pragma unroll
  for (int j = 0; j < 8; ++j) ov[j] = (bf16_t)(v[j] * inv);
  *(bf16x8*)p = ov;
}

// ---------------------------------------------------------------------------
// V transpose: v_tmp (b, l, head*HDIM+hd) -> vT (b*H+head, hd, l)
// ---------------------------------------------------------------------------
__global__ __launch_bounds__(256)
void transpose_v(const bf16_t* __restrict__ vt, bf16_t* __restrict__ vT) {
  __shared__ bf16_t tile[64][65];
  const int z = blockIdx.z, b = z >> 2, head = z & 3;
  const int l0 = blockIdx.x * 64, hd0 = blockIdx.y * 64;
  const int x = threadIdx.x & 63, y4 = threadIdx.x >> 6;
#pragma unroll
  for (int r = 0; r < 64; r += 4) {
    const int l = l0 + y4 + r;
    tile[y4 + r][x] =
        vt[((size_t)b * L_SEQ + l) * DMODEL + head * HDIM + hd0 + x];
  }
  __syncthreads();
#pragma unroll
  for (int r = 0; r < 64; r += 4) {
    const int hd = hd0 + y4 + r;
    vT[((size_t)z * HDIM + hd) * L_SEQ + l0 + x] = tile[x][y4 + r];
  }
}

// ---------------------------------------------------------------------------
// Epilogue functors
// ---------------------------------------------------------------------------
struct EpiBiasF32 {
  float* C; const float* bias; int ldc;
  __device__ __forceinline__ void store(int, int m, int n, float v) const {
    C[(size_t)m * ldc + n] = v + bias[n];
  }
};
struct EpiResBiasF32 {
  float* C; const float* bias; int ldc;
  __device__ __forceinline__ void store(int, int m, int n, float v) const {
    const size_t idx = (size_t)m * ldc + n;
    C[idx] = C[idx] + v + bias[n];
  }
};
struct EpiGeluBf16 {
  bf16_t* C; const float* bias; int ldc;
  __device__ __forceinline__ void store(int, int m, int n, float v) const {
    const float t = v + bias[n];
    const float g = 0.5f * t * (1.0f + erff(t * 0.7071067811865475f));
    C[(size_t)m * ldc + n] = (bf16_t)g;
  }
};
struct EpiQKV {
  bf16_t *q, *k, *vt; const float* bias;
  __device__ __forceinline__ void store(int, int m, int n, float v) const {
    const float t = v + bias[n];
    const int b = m >> 11, l = m & 2047;
    const int which = n >> 10, e = n & 1023;
    const int head = e >> 8, hd = e & 255;
    const bf16_t x = (bf16_t)t;
    if (which == 0)
      q[(((size_t)(b * NHEAD + head)) * L_SEQ + l) * HDIM + hd] = x;
    else if (which == 1)
      k[(((size_t)(b * NHEAD + head)) * L_SEQ + l) * HDIM + hd] = x;
    else
      vt[(size_t)m * DMODEL + e] = x;
  }
};
struct EpiScaleBf16 {
  bf16_t* C; long strideC; int ldc; float scale;
  __device__ __forceinline__ void store(int z, int m, int n, float v) const {
    C[(size_t)z * strideC + (size_t)m * ldc + n] = (bf16_t)(v * scale);
  }
};
struct EpiOBf16 {
  bf16_t* C;
  __device__ __forceinline__ void store(int z, int m, int n, float v) const {
    C[((size_t)(z >> 2) * L_SEQ + m) * DMODEL + (z & 3) * HDIM + n] = (bf16_t)v;
  }
};

// ---------------------------------------------------------------------------
// bf16 GEMM: C[m,n] = sum_k A[m,k]*B[n,k]  (B row-major NxK)
// BM=BN=128, BK=64; 4 waves in 2x2, each 4x4 MFMA 16x16x32, 2 k-steps/iter.
// LDS layout XOR-swizzled: logical (row r, 16B-chunk c) stored at physical
// chunk c^(r&7). Staging permutes the *global* source column per lane (the
// global_load_lds lane->LDS mapping is fixed at lane*16), so fragment
// ds_read_b128 lands 2-way on banks (free) instead of 8/16-way.
// K multiple of 64; lda/ldb multiples of 8.
// ---------------------------------------------------------------------------
template<class Epi>
__global__ __launch_bounds__(256, 3)
void gemm_bt(const bf16_t* __restrict__ A, int lda, long strideA,
             const bf16_t* __restrict__ B, int ldb, long strideB,
             int K, Epi epi) {
  __shared__ bf16_t lsA[128 * 64];
  __shared__ bf16_t lsB[128 * 64];
  const int tid  = threadIdx.x;
  const int wave = tid >> 6, lane = tid & 63;
  const int z = blockIdx.z;
  A += (size_t)z * strideA;
  B += (size_t)z * strideB;
  const int m0 = blockIdx.y * 128, n0 = blockIdx.x * 128;

  // staging: wave covers rows [wave*32 + j*8, +8), j=0..3.
  // lane: row_local = lane>>3, phys chunk p = lane&7 -> logical chunk p^row_local
  const int rl = lane >> 3, p = lane & 7;
  const int csw = (p ^ rl) * 8;                 // swizzled source column (elems)
  const int rbase = wave * 32 + rl;
  const bf16_t* gA = A + (size_t)(m0 + rbase) * lda + csw;
  const bf16_t* gB = B + (size_t)(n0 + rbase) * ldb + csw;
  bf16_t* lA = &lsA[wave * 32 * 64];
  bf16_t* lB = &lsB[wave * 32 * 64];

  const int wm = wave >> 1, wn = wave & 1;
  const int lane15 = lane & 15, quad = lane >> 4;
  const int arow = wm * 64 + lane15;            // + i*16
  const int brow = wn * 64 + lane15;            // + j*16
  const int sw = lane15 & 7;
  const int koff0 = ((quad + 0) ^ sw) * 8;      // kk=0 chunk offset in row
  const int koff1 = ((quad + 4) ^ sw) * 8;      // kk=1

  floatx4 acc[4][4] = {};

  for (int k0 = 0; k0 < K; k0 += 64) {
#pragma unroll
    for (int j = 0; j < 4; ++j) {
      async_cp16(gA + k0 + (size_t)j * 8 * lda, lA + j * 8 * 64);
      async_cp16(gB + k0 + (size_t)j * 8 * ldb, lB + j * 8 * 64);
    }
    __syncthreads();
#pragma unroll
    for (int kk = 0; kk < 2; ++kk) {
      const int ko = kk ? koff1 : koff0;
      bf16x8 af[4], bfr[4];
#pragma unroll
      for (int i = 0; i < 4; ++i)
        af[i] = *(const bf16x8*)&lsA[(arow + i * 16) * 64 + ko];
#pragma unroll
      for (int j = 0; j < 4; ++j)
        bfr[j] = *(const bf16x8*)&lsB[(brow + j * 16) * 64 + ko];
#pragma unroll
      for (int i = 0; i < 4; ++i)
#pragma unroll
        for (int j = 0; j < 4; ++j)
          acc[i][j] = __builtin_amdgcn_mfma_f32_16x16x32_bf16(af[i], bfr[j],
                                                              acc[i][j], 0, 0, 0);
    }
    __syncthreads();
  }

  // epilogue: C/D layout col = lane&15, row = quad*4 + reg (m89-verified)
#pragma unroll
  for (int i = 0; i < 4; ++i) {
    const int mbase = m0 + wm * 64 + i * 16 + quad * 4;
#pragma unroll
    for (int j = 0; j < 4; ++j) {
      const int nloc = n0 + wn * 64 + j * 16 + lane15;
#pragma unroll
      for (int r = 0; r < 4; ++r)
        epi.store(z, mbase + r, nloc, acc[i][j][r]);
    }
  }
}

// ---------------------------------------------------------------------------
// Host launcher
// ---------------------------------------------------------------------------
extern "C" void kernel_launch(void* const* d_in, const int* in_sizes, int n_in,
                              void* d_out, int out_size, void* d_ws, size_t ws_size,
                              hipStream_t stream) {
  const float* x_in  = (const float*)d_in[0];
  const float* w3d   = (const float*)d_in[1];
  const float* b3d   = (const float*)d_in[2];
  const float* ln1g  = (const float*)d_in[3];
  const float* ln1b  = (const float*)d_in[4];
  const float* wqkv  = (const float*)d_in[5];
  const float* bqkv  = (const float*)d_in[6];
  const float* wproj = (const float*)d_in[7];
  const float* bproj = (const float*)d_in[8];
  const float* ln2g  = (const float*)d_in[9];
  const float* ln2b  = (const float*)d_in[10];
  const float* w1    = (const float*)d_in[11];
  const float* b1    = (const float*)d_in[12];
  const float* w2    = (const float*)d_in[13];
  const float* b2    = (const float*)d_in[14];
  const float* lnfg  = (const float*)d_in[15];
  const float* lnfb  = (const float*)d_in[16];
  float* out = (float*)d_out;

  char* ws = (char*)d_ws;
  size_t off = 0;
  auto alloc = [&](size_t bytes) -> void* {
    void* p = ws + off;
    off = (off + bytes + 255) & ~(size_t)255;
    return p;
  };
  float*  h      = (float*) alloc((size_t)MROWS * DMODEL * 4);
  bf16_t* hn     = (bf16_t*)alloc((size_t)MROWS * DMODEL * 2);
  bf16_t* w3db   = (bf16_t*)alloc((size_t)DMODEL * 3 * DMODEL * 2);
  bf16_t* wqkvb  = (bf16_t*)alloc((size_t)NLAYER * 3 * DMODEL * DMODEL * 2);
  bf16_t* wprojb = (bf16_t*)alloc((size_t)NLAYER * DMODEL * DMODEL * 2);
  bf16_t* w1b    = (bf16_t*)alloc((size_t)NLAYER * FFDIM * DMODEL * 2);
  bf16_t* w2b    = (bf16_t*)alloc((size_t)NLAYER * DMODEL * FFDIM * 2);
  char*   r1     = (char*)  alloc(3ull * 16777216);
  bf16_t* xb     = (bf16_t*)r1;
  bf16_t* qb     = (bf16_t*)r1;
  bf16_t* kb     = (bf16_t*)(r1 + 16777216);
  bf16_t* vtmp   = (bf16_t*)(r1 + 2ull * 16777216);
  bf16_t* vT     = (bf16_t*)alloc(16777216);
  bf16_t* ob     = (bf16_t*)alloc(16777216);
  char*   r2     = (char*)  alloc(134217728);
  bf16_t* S      = (bf16_t*)r2;
  bf16_t* f      = (bf16_t*)r2;
  (void)ws_size; (void)in_sizes; (void)n_in; (void)out_size;

  auto cvt = [&](const float* src, bf16_t* dst, size_t n) {
    int n4 = (int)(n / 4);
    cvt_f32_bf16<<<(n4 + 255) / 256, 256, 0, stream>>>(src, dst, n4);
  };
  cvt(x_in,  xb,     (size_t)MROWS * 3 * DMODEL);
  cvt(w3d,   w3db,   (size_t)DMODEL * 3 * DMODEL);
  cvt(wqkv,  wqkvb,  (size_t)NLAYER * 3 * DMODEL * DMODEL);
  cvt(wproj, wprojb, (size_t)NLAYER * DMODEL * DMODEL);
  cvt(w1,    w1b,    (size_t)NLAYER * FFDIM * DMODEL);
  cvt(w2,    w2b,    (size_t)NLAYER * DMODEL * FFDIM);

  // initial projection: h = x @ w3d^T + b3d
  gemm_bt<<<dim3(DMODEL / 128, MROWS / 128, 1), 256, 0, stream>>>(
      xb, 3 * DMODEL, 0L, w3db, 3 * DMODEL, 0L, 3 * DMODEL,
      EpiBiasF32{h, b3d, DMODEL});

  for (int i = 0; i < NLAYER; ++i) {
    ln_kernel<true><<<MROWS, 256, 0, stream>>>(h, ln1g + i * DMODEL,
                                               ln1b + i * DMODEL, hn);
    gemm_bt<<<dim3(3 * DMODEL / 128, MROWS / 128, 1), 256, 0, stream>>>(
        hn, DMODEL, 0L, wqkvb + (size_t)i * 3 * DMODEL * DMODEL, DMODEL, 0L,
        DMODEL, EpiQKV{qb, kb, vtmp, bqkv + i * 3 * DMODEL});
    transpose_v<<<dim3(L_SEQ / 64, HDIM / 64, BATCH * NHEAD), 256, 0, stream>>>(
        vtmp, vT);
    gemm_bt<<<dim3(L_SEQ / 128, L_SEQ / 128, BATCH * NHEAD), 256, 0, stream>>>(
        qb, HDIM, (long)L_SEQ * HDIM, kb, HDIM, (long)L_SEQ * HDIM, HDIM,
        EpiScaleBf16{S, (long)L_SEQ * L_SEQ, L_SEQ, 0.0625f});
    softmax_kernel<<<BATCH * NHEAD * L_SEQ, 256, 0, stream>>>(S);
    gemm_bt<<<dim3(HDIM / 128, L_SEQ / 128, BATCH * NHEAD), 256, 0, stream>>>(
        S, L_SEQ, (long)L_SEQ * L_SEQ, vT, L_SEQ, (long)HDIM * L_SEQ, L_SEQ,
        EpiOBf16{ob});
    gemm_bt<<<dim3(DMODEL / 128, MROWS / 128, 1), 256, 0, stream>>>(
        ob, DMODEL, 0L, wprojb + (size_t)i * DMODEL * DMODEL, DMODEL, 0L,
        DMODEL, EpiResBiasF32{h, bproj + i * DMODEL, DMODEL});
    ln_kernel<true><<<MROWS, 256, 0, stream>>>(h, ln2g + i * DMODEL,
                                               ln2b + i * DMODEL, hn);
    gemm_bt<<<dim3(FFDIM / 128, MROWS / 128, 1), 256, 0, stream>>>(
        hn, DMODEL, 0L, w1b + (size_t)i * FFDIM * DMODEL, DMODEL, 0L, DMODEL,
        EpiGeluBf16{f, b1 + i * FFDIM, FFDIM});
    gemm_bt<<<dim3(DMODEL / 128, MROWS / 128, 1), 256, 0, stream>>>(
        f, FFDIM, 0L, w2b + (size_t)i * DMODEL * FFDIM, FFDIM, 0L, FFDIM,
        EpiResBiasF32{h, b2 + i * DMODEL, DMODEL});
  }

  ln_kernel<false><<<MROWS, 256, 0, stream>>>(h, lnfg, lnfb, out);
}

// Round 3
// 1280.833 us; speedup vs baseline: 1.1416x; 1.0326x over previous
//
#include <hip/hip_runtime.h>
#include <cstdint>
#include <cstddef>

// Problem constants
#define BATCH   4
#define L_SEQ   2048
#define DMODEL  1024
#define NHEAD   4
#define HDIM    256
#define FFDIM   4096
#define MROWS   (BATCH * L_SEQ)   // 8192
#define NLAYER  2

typedef __bf16 bf16_t;
typedef __bf16 bf16x8 __attribute__((ext_vector_type(8)));
typedef __bf16 bf16x4 __attribute__((ext_vector_type(4)));
typedef float  floatx4 __attribute__((ext_vector_type(4)));

// ---------------------------------------------------------------------------
// async global->LDS 16B copy. LDS dest = wave-uniform base + lane*16 (HW rule).
// ---------------------------------------------------------------------------
__device__ __forceinline__ void async_cp16(const void* g, void* l) {
  auto gp = reinterpret_cast<__attribute__((address_space(1))) void*>(
      reinterpret_cast<uintptr_t>(g));
  auto lp = reinterpret_cast<__attribute__((address_space(3))) void*>(
      reinterpret_cast<uintptr_t>(l));
  __builtin_amdgcn_global_load_lds(gp, lp, 16, 0, 0);
}

// ---------------------------------------------------------------------------
// f32 -> bf16 convert (vectorized)
// ---------------------------------------------------------------------------
__global__ __launch_bounds__(256)
void cvt_f32_bf16(const float* __restrict__ in, bf16_t* __restrict__ out, int n4) {
  int i = blockIdx.x * 256 + threadIdx.x;
  if (i >= n4) return;
  float4 v = ((const float4*)in)[i];
  bf16x4 ov = { (bf16_t)v.x, (bf16_t)v.y, (bf16_t)v.z, (bf16_t)v.w };
  ((bf16x4*)out)[i] = ov;
}

// ---------------------------------------------------------------------------
// LayerNorm: one block (256 threads) per row of D=1024, fp32 math.
// ---------------------------------------------------------------------------
template<bool BF16OUT>
__global__ __launch_bounds__(256)
void ln_kernel(const float* __restrict__ x, const float* __restrict__ gw,
               const float* __restrict__ bw, void* __restrict__ outp) {
  const int row = blockIdx.x;
  const int tid = threadIdx.x;
  const float4 v = ((const float4*)(x + (size_t)row * DMODEL))[tid];
  float s  = v.x + v.y + v.z + v.w;
  float ss = v.x * v.x + v.y * v.y + v.z * v.z + v.w * v.w;
#pragma unroll
  for (int o = 32; o > 0; o >>= 1) {
    s  += __shfl_xor(s, o);
    ss += __shfl_xor(ss, o);
  }
  __shared__ float red0[4], red1[4];
  const int wv = tid >> 6;
  if ((tid & 63) == 0) { red0[wv] = s; red1[wv] = ss; }
  __syncthreads();
  s  = red0[0] + red0[1] + red0[2] + red0[3];
  ss = red1[0] + red1[1] + red1[2] + red1[3];
  const float mu  = s * (1.0f / DMODEL);
  const float var = ss * (1.0f / DMODEL) - mu * mu;
  const float rs  = rsqrtf(var + 1e-5f);
  const float4 g4 = ((const float4*)gw)[tid];
  const float4 b4 = ((const float4*)bw)[tid];
  const float o0 = (v.x - mu) * rs * g4.x + b4.x;
  const float o1 = (v.y - mu) * rs * g4.y + b4.y;
  const float o2 = (v.z - mu) * rs * g4.z + b4.z;
  const float o3 = (v.w - mu) * rs * g4.w + b4.w;
  if (BF16OUT) {
    bf16x4 ov = { (bf16_t)o0, (bf16_t)o1, (bf16_t)o2, (bf16_t)o3 };
    ((bf16x4*)outp)[(size_t)row * (DMODEL / 4) + tid] = ov;
  } else {
    float4 ov = { o0, o1, o2, o3 };
    ((float4*)outp)[(size_t)row * (DMODEL / 4) + tid] = ov;
  }
}

// ---------------------------------------------------------------------------
// Flash attention (non-causal). Grid (16 q-tiles, 16 z), 512 threads = 8 waves.
// Each wave owns 16 q-rows (q = lane&15 within wave). Q held in registers as
// MFMA B-fragments. Per 64-key iteration:
//   stage K-tile (64x256, 32KB) + V^T-tile (256x64, 32KB) via global_load_lds,
//   S^T = K @ Q^T  (C: col=lane15=q, row=quad*4+r=key)   [orientation chosen so
//     softmax key-reduction = 2 shuffles (xor 16,32) and P packs as b64 writes]
//   online softmax fp32, P (bf16) overlaid into K-region (LDS stays 64KB),
//   O^T += V^T @ P  (C: col=lane15=q, row=quad*4+r=hd), accumulate 64 VGPRs.
// All LDS tiles XOR-swizzled (16B chunk c stored at c^(row&7)) -> conflict-free.
// ---------------------------------------------------------------------------
__global__ __launch_bounds__(512, 2)
void flash_attn(const bf16_t* __restrict__ Q, const bf16_t* __restrict__ K,
                const bf16_t* __restrict__ VT, bf16_t* __restrict__ O) {
  __shared__ bf16_t lsK[64 * 256];   // 32KB; doubles as P after mid-barrier
  __shared__ bf16_t lsV[256 * 64];   // 32KB (V^T tile: row=hd, col=key)
  const int tid = threadIdx.x, wave = tid >> 6, lane = tid & 63;
  const int lane15 = lane & 15, quad = lane >> 4;
  const int z = blockIdx.y, qt = blockIdx.x;
  const bf16_t* Qz = Q + (size_t)z * L_SEQ * HDIM;
  const bf16_t* Kz = K + (size_t)z * L_SEQ * HDIM;
  const bf16_t* Vz = VT + (size_t)z * HDIM * L_SEQ;

  const int qrow = qt * 128 + wave * 16 + lane15;
  // Q fragments: B[n=lane15][k=quad*8+j], 8 k-chunks of 32
  bf16x8 qf[8];
#pragma unroll
  for (int kc = 0; kc < 8; ++kc)
    qf[kc] = *(const bf16x8*)(Qz + (size_t)qrow * HDIM + kc * 32 + quad * 8);

  floatx4 oacc[16] = {};        // O^T[hd=mf*16+quad*4+r][q=lane15]
  float m_run = -1e30f, l_run = 0.f;

  // staging lane coords
  const int krl = lane >> 5, kp = lane & 31;   // K: 2 rows/instr, 32 chunks/row
  const int vrl = lane >> 3, vp = lane & 7;    // V: 8 rows/instr, 8 chunks/row
  bf16_t* Pw = lsK + wave * 1024;              // P slice: 16 q x 64 keys (2KB)

  for (int kt = 0; kt < L_SEQ; kt += 64) {
    // ---- stage K-tile + V^T-tile (8 async_cp16 per wave) ----
#pragma unroll
    for (int j = 0; j < 4; ++j) {
      const int i = wave * 4 + j;
      const int r = 2 * i + krl;
      const int col = ((kp & 24) | ((kp ^ r) & 7)) * 8;
      async_cp16(Kz + (size_t)(kt + r) * HDIM + col, lsK + i * 512);
      const int rv = 8 * i + vrl;
      const int colv = ((vp ^ rv) & 7) * 8;
      async_cp16(Vz + (size_t)rv * L_SEQ + kt + colv, lsV + i * 512);
    }
    __syncthreads();

    // ---- S^T = K @ Q^T ----
    floatx4 sacc[4] = {};
#pragma unroll
    for (int kc = 0; kc < 8; ++kc) {
#pragma unroll
      for (int mf = 0; mf < 4; ++mf) {
        const int rr = mf * 16 + lane15;
        const int c = kc * 4 + quad;
        const int phys = (c & 24) | ((c ^ rr) & 7);
        bf16x8 af = *(const bf16x8*)(lsK + rr * 256 + phys * 8);
        sacc[mf] = __builtin_amdgcn_mfma_f32_16x16x32_bf16(af, qf[kc],
                                                           sacc[mf], 0, 0, 0);
      }
    }

    // ---- online softmax (per q = lane15; keys spread over quads+regs) ----
    float p[4][4];
    float mx = -1e30f;
#pragma unroll
    for (int mf = 0; mf < 4; ++mf)
#pragma unroll
      for (int r = 0; r < 4; ++r) {
        p[mf][r] = sacc[mf][r] * 0.0625f;   // 1/sqrt(256)
        mx = fmaxf(mx, p[mf][r]);
      }
    mx = fmaxf(mx, __shfl_xor(mx, 16));
    mx = fmaxf(mx, __shfl_xor(mx, 32));
    const float m_new = fmaxf(m_run, mx);
    const float alpha = __expf(m_run - m_new);
    float rs = 0.f;
#pragma unroll
    for (int mf = 0; mf < 4; ++mf)
#pragma unroll
      for (int r = 0; r < 4; ++r) {
        p[mf][r] = __expf(p[mf][r] - m_new);
        rs += p[mf][r];
      }
    rs += __shfl_xor(rs, 16);
    rs += __shfl_xor(rs, 32);
    l_run = l_run * alpha + rs;
    m_run = m_new;
#pragma unroll
    for (int mf = 0; mf < 16; ++mf)
#pragma unroll
      for (int r = 0; r < 4; ++r) oacc[mf][r] *= alpha;

    __syncthreads();   // all waves done reading K-tile; safe to overlay P

    // ---- write P (rows q=lane15, 64 keys; swizzled b64 writes) ----
#pragma unroll
    for (int mf = 0; mf < 4; ++mf) {
      bf16x4 pk = { (bf16_t)p[mf][0], (bf16_t)p[mf][1],
                    (bf16_t)p[mf][2], (bf16_t)p[mf][3] };
      const int c = mf * 2 + (quad >> 1);          // logical chunk of key group
      const int phys = c ^ (lane15 & 7);
      *(bf16x4*)(Pw + lane15 * 64 + phys * 8 + (quad & 1) * 4) = pk;
    }

    // ---- O^T += V^T @ P ----
#pragma unroll
    for (int kc = 0; kc < 2; ++kc) {
      const int cb = kc * 4 + quad;
      const int pb = cb ^ (lane15 & 7);
      bf16x8 bfr = *(const bf16x8*)(Pw + lane15 * 64 + pb * 8);
#pragma unroll
      for (int mf = 0; mf < 16; ++mf) {
        const int rr = mf * 16 + lane15;
        const int phys = cb ^ (rr & 7);
        bf16x8 af = *(const bf16x8*)(lsV + rr * 64 + phys * 8);
        oacc[mf] = __builtin_amdgcn_mfma_f32_16x16x32_bf16(af, bfr,
                                                           oacc[mf], 0, 0, 0);
      }
    }
    __syncthreads();   // P/V reads done before next staging overwrites
  }

  // ---- normalize and write O: ob[b][l][head*256+hd] ----
  const float inv = 1.0f / l_run;
  const int b = z >> 2, head = z & 3;
  bf16_t* orow = O + ((size_t)b * L_SEQ + qrow) * DMODEL + head * HDIM;
#pragma unroll
  for (int mf = 0; mf < 16; ++mf) {
    const int hd = mf * 16 + quad * 4;
    bf16x4 ov = { (bf16_t)(oacc[mf][0] * inv), (bf16_t)(oacc[mf][1] * inv),
                  (bf16_t)(oacc[mf][2] * inv), (bf16_t)(oacc[mf][3] * inv) };
    *(bf16x4*)(orow + hd) = ov;
  }
}

// ---------------------------------------------------------------------------
// Epilogue functors — store4 gets 4 consecutive m (rows), fixed n
// ---------------------------------------------------------------------------
struct EpiBiasF32 {
  float* C; const float* bias; int ldc;
  __device__ __forceinline__ void store4(int, int m, int n, floatx4 v) const {
    const float bb = bias[n];
#pragma unroll
    for (int r = 0; r < 4; ++r) C[(size_t)(m + r) * ldc + n] = v[r] + bb;
  }
};
struct EpiResBiasF32 {
  float* C; const float* bias; int ldc;
  __device__ __forceinline__ void store4(int, int m, int n, floatx4 v) const {
    const float bb = bias[n];
#pragma unroll
    for (int r = 0; r < 4; ++r) {
      const size_t idx = (size_t)(m + r) * ldc + n;
      C[idx] = C[idx] + v[r] + bb;
    }
  }
};
struct EpiGeluBf16 {
  bf16_t* C; const float* bias; int ldc;
  __device__ __forceinline__ void store4(int, int m, int n, floatx4 v) const {
    const float bb = bias[n];
#pragma unroll
    for (int r = 0; r < 4; ++r) {
      const float t = v[r] + bb;
      const float g = 0.5f * t * (1.0f + erff(t * 0.7071067811865475f));
      C[(size_t)(m + r) * ldc + n] = (bf16_t)g;
    }
  }
};
struct EpiQKV {   // q,k -> (z,l,hd); v -> vT (z,hd,l) DIRECTLY TRANSPOSED
  bf16_t *q, *k, *vT; const float* bias;
  __device__ __forceinline__ void store4(int, int m, int n, floatx4 v) const {
    const float bb = bias[n];
    const int b = m >> 11, l = m & 2047;        // rows m..m+3 share b (m%4==0)
    const int which = n >> 10, e = n & 1023;
    const int head = e >> 8, hd = e & 255;
    const int z = b * NHEAD + head;
    if (which == 2) {
      bf16x4 ov = { (bf16_t)(v[0] + bb), (bf16_t)(v[1] + bb),
                    (bf16_t)(v[2] + bb), (bf16_t)(v[3] + bb) };
      *(bf16x4*)(vT + ((size_t)z * HDIM + hd) * L_SEQ + l) = ov;
    } else {
      bf16_t* dst = (which == 0 ? q : k) + ((size_t)z * L_SEQ + l) * HDIM + hd;
#pragma unroll
      for (int r = 0; r < 4; ++r) dst[(size_t)r * HDIM] = (bf16_t)(v[r] + bb);
    }
  }
};

// ---------------------------------------------------------------------------
// bf16 GEMM: C[m,n] = sum_k A[m,k]*B[n,k]  (B row-major NxK)
// BM=BN=128, BK=64; 4 waves 2x2, each 4x4 MFMA 16x16x32. XOR-swizzled LDS.
// ---------------------------------------------------------------------------
template<class Epi>
__global__ __launch_bounds__(256, 3)
void gemm_bt(const bf16_t* __restrict__ A, int lda, long strideA,
             const bf16_t* __restrict__ B, int ldb, long strideB,
             int K, Epi epi) {
  __shared__ bf16_t lsA[128 * 64];
  __shared__ bf16_t lsB[128 * 64];
  const int tid  = threadIdx.x;
  const int wave = tid >> 6, lane = tid & 63;
  const int z = blockIdx.z;
  A += (size_t)z * strideA;
  B += (size_t)z * strideB;
  const int m0 = blockIdx.y * 128, n0 = blockIdx.x * 128;

  const int rl = lane >> 3, p = lane & 7;
  const int csw = (p ^ rl) * 8;
  const int rbase = wave * 32 + rl;
  const bf16_t* gA = A + (size_t)(m0 + rbase) * lda + csw;
  const bf16_t* gB = B + (size_t)(n0 + rbase) * ldb + csw;
  bf16_t* lA = &lsA[wave * 32 * 64];
  bf16_t* lB = &lsB[wave * 32 * 64];

  const int wm = wave >> 1, wn = wave & 1;
  const int lane15 = lane & 15, quad = lane >> 4;
  const int arow = wm * 64 + lane15;
  const int brow = wn * 64 + lane15;
  const int sw = lane15 & 7;
  const int koff0 = ((quad + 0) ^ sw) * 8;
  const int koff1 = ((quad + 4) ^ sw) * 8;

  floatx4 acc[4][4] = {};

  for (int k0 = 0; k0 < K; k0 += 64) {
#pragma unroll
    for (int j = 0; j < 4; ++j) {
      async_cp16(gA + k0 + (size_t)j * 8 * lda, lA + j * 8 * 64);
      async_cp16(gB + k0 + (size_t)j * 8 * ldb, lB + j * 8 * 64);
    }
    __syncthreads();
#pragma unroll
    for (int kk = 0; kk < 2; ++kk) {
      const int ko = kk ? koff1 : koff0;
      bf16x8 af[4], bfr[4];
#pragma unroll
      for (int i = 0; i < 4; ++i)
        af[i] = *(const bf16x8*)&lsA[(arow + i * 16) * 64 + ko];
#pragma unroll
      for (int j = 0; j < 4; ++j)
        bfr[j] = *(const bf16x8*)&lsB[(brow + j * 16) * 64 + ko];
#pragma unroll
      for (int i = 0; i < 4; ++i)
#pragma unroll
        for (int j = 0; j < 4; ++j)
          acc[i][j] = __builtin_amdgcn_mfma_f32_16x16x32_bf16(af[i], bfr[j],
                                                              acc[i][j], 0, 0, 0);
    }
    __syncthreads();
  }

#pragma unroll
  for (int i = 0; i < 4; ++i) {
    const int mbase = m0 + wm * 64 + i * 16 + quad * 4;
#pragma unroll
    for (int j = 0; j < 4; ++j) {
      const int nloc = n0 + wn * 64 + j * 16 + lane15;
      epi.store4(z, mbase, nloc, acc[i][j]);
    }
  }
}

// ---------------------------------------------------------------------------
// Host launcher
// ---------------------------------------------------------------------------
extern "C" void kernel_launch(void* const* d_in, const int* in_sizes, int n_in,
                              void* d_out, int out_size, void* d_ws, size_t ws_size,
                              hipStream_t stream) {
  const float* x_in  = (const float*)d_in[0];
  const float* w3d   = (const float*)d_in[1];
  const float* b3d   = (const float*)d_in[2];
  const float* ln1g  = (const float*)d_in[3];
  const float* ln1b  = (const float*)d_in[4];
  const float* wqkv  = (const float*)d_in[5];
  const float* bqkv  = (const float*)d_in[6];
  const float* wproj = (const float*)d_in[7];
  const float* bproj = (const float*)d_in[8];
  const float* ln2g  = (const float*)d_in[9];
  const float* ln2b  = (const float*)d_in[10];
  const float* w1    = (const float*)d_in[11];
  const float* b1    = (const float*)d_in[12];
  const float* w2    = (const float*)d_in[13];
  const float* b2    = (const float*)d_in[14];
  const float* lnfg  = (const float*)d_in[15];
  const float* lnfb  = (const float*)d_in[16];
  float* out = (float*)d_out;

  char* ws = (char*)d_ws;
  size_t off = 0;
  auto alloc = [&](size_t bytes) -> void* {
    void* p = ws + off;
    off = (off + bytes + 255) & ~(size_t)255;
    return p;
  };
  float*  h      = (float*) alloc((size_t)MROWS * DMODEL * 4);        // 32 MB
  bf16_t* hn     = (bf16_t*)alloc((size_t)MROWS * DMODEL * 2);        // 16 MB
  bf16_t* w3db   = (bf16_t*)alloc((size_t)DMODEL * 3 * DMODEL * 2);
  bf16_t* wqkvb  = (bf16_t*)alloc((size_t)NLAYER * 3 * DMODEL * DMODEL * 2);
  bf16_t* wprojb = (bf16_t*)alloc((size_t)NLAYER * DMODEL * DMODEL * 2);
  bf16_t* w1b    = (bf16_t*)alloc((size_t)NLAYER * FFDIM * DMODEL * 2);
  bf16_t* w2b    = (bf16_t*)alloc((size_t)NLAYER * DMODEL * FFDIM * 2);
  bf16_t* xb     = (bf16_t*)alloc((size_t)MROWS * 3 * DMODEL * 2);    // 48 MB
  bf16_t* qb     = (bf16_t*)alloc((size_t)MROWS * DMODEL * 2);        // 16 MB
  bf16_t* kb     = (bf16_t*)alloc((size_t)MROWS * DMODEL * 2);        // 16 MB
  bf16_t* vT     = (bf16_t*)alloc((size_t)MROWS * DMODEL * 2);        // 16 MB
  bf16_t* ob     = (bf16_t*)alloc((size_t)MROWS * DMODEL * 2);        // 16 MB
  bf16_t* f      = (bf16_t*)alloc((size_t)MROWS * FFDIM * 2);         // 64 MB
  (void)ws_size; (void)in_sizes; (void)n_in; (void)out_size;

  auto cvt = [&](const float* src, bf16_t* dst, size_t n) {
    int n4 = (int)(n / 4);
    cvt_f32_bf16<<<(n4 + 255) / 256, 256, 0, stream>>>(src, dst, n4);
  };
  cvt(x_in,  xb,     (size_t)MROWS * 3 * DMODEL);
  cvt(w3d,   w3db,   (size_t)DMODEL * 3 * DMODEL);
  cvt(wqkv,  wqkvb,  (size_t)NLAYER * 3 * DMODEL * DMODEL);
  cvt(wproj, wprojb, (size_t)NLAYER * DMODEL * DMODEL);
  cvt(w1,    w1b,    (size_t)NLAYER * FFDIM * DMODEL);
  cvt(w2,    w2b,    (size_t)NLAYER * DMODEL * FFDIM);

  // initial projection: h = x @ w3d^T + b3d
  gemm_bt<<<dim3(DMODEL / 128, MROWS / 128, 1), 256, 0, stream>>>(
      xb, 3 * DMODEL, 0L, w3db, 3 * DMODEL, 0L, 3 * DMODEL,
      EpiBiasF32{h, b3d, DMODEL});

  for (int i = 0; i < NLAYER; ++i) {
    ln_kernel<true><<<MROWS, 256, 0, stream>>>(h, ln1g + i * DMODEL,
                                               ln1b + i * DMODEL, hn);
    // qkv: q,k -> (z,l,hd); v -> vT (z,hd,l) transposed in epilogue
    gemm_bt<<<dim3(3 * DMODEL / 128, MROWS / 128, 1), 256, 0, stream>>>(
        hn, DMODEL, 0L, wqkvb + (size_t)i * 3 * DMODEL * DMODEL, DMODEL, 0L,
        DMODEL, EpiQKV{qb, kb, vT, bqkv + i * 3 * DMODEL});
    // fused flash attention -> ob
    flash_attn<<<dim3(L_SEQ / 128, BATCH * NHEAD), 512, 0, stream>>>(
        qb, kb, vT, ob);
    gemm_bt<<<dim3(DMODEL / 128, MROWS / 128, 1), 256, 0, stream>>>(
        ob, DMODEL, 0L, wprojb + (size_t)i * DMODEL * DMODEL, DMODEL, 0L,
        DMODEL, EpiResBiasF32{h, bproj + i * DMODEL, DMODEL});
    ln_kernel<true><<<MROWS, 256, 0, stream>>>(h, ln2g + i * DMODEL,
                                               ln2b + i * DMODEL, hn);
    gemm_bt<<<dim3(FFDIM / 128, MROWS / 128, 1), 256, 0, stream>>>(
        hn, DMODEL, 0L, w1b + (size_t)i * FFDIM * DMODEL, DMODEL, 0L, DMODEL,
        EpiGeluBf16{f, b1 + i * FFDIM, FFDIM});
    gemm_bt<<<dim3(DMODEL / 128, MROWS / 128, 1), 256, 0, stream>>>(
        f, FFDIM, 0L, w2b + (size_t)i * DMODEL * FFDIM, FFDIM, 0L, FFDIM,
        EpiResBiasF32{h, b2 + i * DMODEL, DMODEL});
  }

  ln_kernel<false><<<MROWS, 256, 0, stream>>>(h, lnfg, lnfb, out);
}